// Round 12
// baseline (486.810 us; speedup 1.0000x reference)
//
#include <hip/hip_runtime.h>
#include <hip/hip_bf16.h>
#include <stdint.h>

typedef unsigned short u16;
typedef __attribute__((ext_vector_type(8))) __bf16 bf16x8;
typedef __attribute__((ext_vector_type(4))) float f32x4;

#define NTOK 8192
#define NIN  1024
#define NOUT 1024
#define KTOT 9216   // NIN (base) + NIN*8 (spline bases)
#define BM 128
#define BN 256
#define BK 64
#define NT (KTOT / BK)        // 144
#define BBUF (BN * BK)        // 16384 u16 = 32 KiB per B K-tile buffer

#define PB_BLOCKS 1024        // prep_base: 32x32 transpose tiles
#define PS_BLOCKS 4096        // prep_spline: NOUT*NIN/256
#define BA_BLOCKS 32768       // build_a: NTOK*NIN/256

__device__ __forceinline__ u16 f2bf(float f) {
  union { float f; unsigned u; } v; v.f = f;
  unsigned r = v.u + 0x7FFFu + ((v.u >> 16) & 1u);   // RNE
  return (u16)(r >> 16);
}

__device__ __forceinline__ void gload_lds16(const void* g, void* l) {
  __builtin_amdgcn_global_load_lds(
      (__attribute__((address_space(1))) void*)(uintptr_t)g,
      (__attribute__((address_space(3))) void*)(uintptr_t)l, 16, 0, 0);
}

// ---------------- fused prep (unchanged, proven) ----------------
__global__ void prep_all(const float* __restrict__ X, const float* __restrict__ W,
                         const float* __restrict__ SW, const float* __restrict__ SS,
                         u16* __restrict__ Bt, u16* __restrict__ A) {
  __shared__ float tile[32][33];
  const int b = blockIdx.x;
  const int tid = threadIdx.x;

  if (b < PB_BLOCKS) {
    int i0 = (b & 31) * 32, o0 = (b >> 5) * 32;
    int tx = tid & 31, ty = tid >> 5;            // 32x8
#pragma unroll
    for (int r = 0; r < 4; ++r)
      tile[ty + 8 * r][tx] = W[(size_t)(i0 + ty + 8 * r) * NOUT + o0 + tx];
    __syncthreads();
#pragma unroll
    for (int r = 0; r < 4; ++r)
      Bt[(size_t)(o0 + ty + 8 * r) * KTOT + i0 + tx] = f2bf(tile[tx][ty + 8 * r]);
  } else if (b < PB_BLOCKS + PS_BLOCKS) {
    int idx = (b - PB_BLOCKS) * 256 + tid;       // over NOUT*NIN
    int o = idx >> 10, i = idx & 1023;
    float s = SS[idx];
    const float4* p = (const float4*)(SW + (size_t)idx * 8);
    float4 a = p[0], c = p[1];
    union { u16 us[8]; uint4 v; } pk;
    pk.us[0] = f2bf(a.x * s); pk.us[1] = f2bf(a.y * s);
    pk.us[2] = f2bf(a.z * s); pk.us[3] = f2bf(a.w * s);
    pk.us[4] = f2bf(c.x * s); pk.us[5] = f2bf(c.y * s);
    pk.us[6] = f2bf(c.z * s); pk.us[7] = f2bf(c.w * s);
    *(uint4*)(Bt + (size_t)o * KTOT + NIN + (size_t)i * 8) = pk.v;
  } else {
    int idx = (b - PB_BLOCKS - PS_BLOCKS) * 256 + tid;   // over NTOK*NIN
    int n = idx >> 10, i = idx & 1023;
    float x = X[idx];
    float sx = x / (1.f + __expf(-x));
    A[(size_t)n * KTOT + i] = f2bf(sx);
    float bb[11];
#pragma unroll
    for (int j = 0; j < 11; ++j) {
      float gj  = 0.4f * j - 2.2f;
      float gj1 = 0.4f * (j + 1) - 2.2f;
      bb[j] = (x >= gj && x < gj1) ? 1.f : 0.f;
    }
#pragma unroll
    for (int k = 1; k <= 3; ++k) {
      float inv = 1.f / (0.4f * k);
#pragma unroll
      for (int j = 0; j + k < 11; ++j) {
        float gj = 0.4f * j - 2.2f;
        float left  = (x - gj) * inv;
        float right = (0.4f * (j + k + 1) - 2.2f - x) * inv;
        bb[j] = left * bb[j] + right * bb[j + 1];
      }
    }
    union { u16 us[8]; uint4 v; } pk;
#pragma unroll
    for (int j = 0; j < 8; ++j) pk.us[j] = f2bf(bb[j]);
    *(uint4*)(A + (size_t)n * KTOT + NIN + (size_t)i * 8) = pk.v;
  }
}

// ---------------- GEMM: A direct global->reg (L1-served), B via LDS ----------------
// C[n][o] = sum_k A[n][k]*Bt[o][k].  BM=128 x BN=256, BK=64, 8 waves (2Mx4N).
// A fragments: per-wave global_load_dwordx4, line-coalesced (16 rows x 64B), identical
// addresses across the 4 N-waves -> L1 serves the reuse. Double-buffered reg sets,
// distance 1, loop 2x-unrolled for static indexing (rule #20).
// B: LDS triple-buffer, distance 2, XOR-swizzled (unchanged from r11).
// Per-thread VMEM per iter: 8 A-loads then 4 B-stages. Compiler inserts the precise
// A-wait before MFMA use. Manual counted wait before barrier (B(t+1) landed):
// younger-than-B(t+1) = A(t+1) 8 + B(t+2) 4 -> vmcnt(12); t==NT-2 -> 8; last -> 0.

__global__ __launch_bounds__(512, 2) void kan_gemm(const u16* __restrict__ A,
                                                   const u16* __restrict__ Bt,
                                                   float* __restrict__ C) {
  __shared__ u16 lds[3 * BBUF];   // 96 KiB, B only
  const int tid = threadIdx.x;
  const int w = tid >> 6, l = tid & 63;
  const int wr = w >> 2, wc = w & 3;        // wave grid 2M x 4N
  const int l4 = l >> 4, lc = l & 15;

  // XCD-bijective swizzle: 2 XCDs per bn panel, bm walks within XCD
  const int bid = blockIdx.x;
  const int xcd = bid & 7, jj = bid >> 3;   // jj in 0..31
  const int bn = xcd >> 1;                  // 0..3
  const int bm = (xcd & 1) * 32 + jj;       // 0..63

  const u16* Bb = Bt + (size_t)bn * BN * KTOT;
  // per-thread A fragment base: row = bm*128 + wr*64 + m*16 + lc, chunk offset l4*8
  const u16* aBase = A + (size_t)(bm * 128 + wr * 64 + lc) * KTOT + l4 * 8;
#define MSTRIDE ((size_t)16 * KTOT)

  // B staging: chunk c -> row r=c>>3, slot s=c&7; source pre-swizzled s^(r&7),
  // LDS linear dest (rule #21)
  int srcB[4], dstB[4];
#pragma unroll
  for (int it = 0; it < 4; ++it) {
    int c = it * 512 + tid, r = c >> 3, s = (c & 7) ^ (r & 7);
    srcB[it] = r * KTOT + s * 8;
    dstB[it] = (it * 512 + w * 64) * 8;     // wave-uniform base + lane*16B
  }

  int rB[4];
#pragma unroll
  for (int n = 0; n < 4; ++n) rB[n] = wc * 64 + n * 16 + lc;

  f32x4 acc[4][4];
#pragma unroll
  for (int m = 0; m < 4; ++m)
#pragma unroll
    for (int n = 0; n < 4; ++n)
      acc[m][n] = f32x4{0.f, 0.f, 0.f, 0.f};

  bf16x8 pA0[4][2], pA1[4][2];

  // prologue: A(0) -> pA0; stage B(0)->buf0, B(1)->buf1; drain A0+B0 (B1 may fly)
#pragma unroll
  for (int m = 0; m < 4; ++m)
#pragma unroll
    for (int kk = 0; kk < 2; ++kk)
      pA0[m][kk] = *(const bf16x8*)(aBase + m * MSTRIDE + kk * 32);
#pragma unroll
  for (int it = 0; it < 4; ++it) gload_lds16(Bb + srcB[it], &lds[dstB[it]]);
#pragma unroll
  for (int it = 0; it < 4; ++it) gload_lds16(Bb + srcB[it] + BK, &lds[BBUF + dstB[it]]);
  asm volatile("s_waitcnt vmcnt(4)" ::: "memory");
  __builtin_amdgcn_s_barrier();

  int cur = 0;
#pragma unroll 1
  for (int tp = 0; tp < NT / 2; ++tp) {
    // ================= even half: t = 2*tp, consume pA0, load pA1 =================
    {
      const int t = 2 * tp;
      const int curo = cur * BBUF;
      const int nxto = ((cur == 0) ? 2 : cur - 1) * BBUF;   // (t+2)%3
      const u16* aT1 = aBase + (size_t)(t + 1) * BK;

      // (a) issue A(t+1) -> pA1   (t+1 <= NT-1 always here since t even <= NT-2)
#pragma unroll
      for (int m = 0; m < 4; ++m)
#pragma unroll
        for (int kk = 0; kk < 2; ++kk)
          pA1[m][kk] = *(const bf16x8*)(aT1 + m * MSTRIDE + kk * 32);
      // (b) stage B(t+2)
      if (t + 2 < NT) {
        const int k0n = (t + 2) * BK;
#pragma unroll
        for (int it = 0; it < 4; ++it) gload_lds16(Bb + srcB[it] + k0n, &lds[nxto + dstB[it]]);
      }
      __builtin_amdgcn_sched_barrier(0);
      // (c) ds_read B(t) fragments
      bf16x8 b_frag[4][2];
#pragma unroll
      for (int n = 0; n < 4; ++n)
#pragma unroll
        for (int kk = 0; kk < 2; ++kk)
          b_frag[n][kk] = *(const bf16x8*)&lds[curo + rB[n] * 64 + (((kk * 4 + l4) ^ (rB[n] & 7)) * 8)];
      asm volatile("s_waitcnt lgkmcnt(0)" ::: "memory");
      __builtin_amdgcn_sched_barrier(0);
      __builtin_amdgcn_s_setprio(1);
#pragma unroll
      for (int kk = 0; kk < 2; ++kk)
#pragma unroll
        for (int m = 0; m < 4; ++m)
#pragma unroll
          for (int n = 0; n < 4; ++n)
            acc[m][n] = __builtin_amdgcn_mfma_f32_16x16x32_bf16(pA0[m][kk], b_frag[n][kk], acc[m][n], 0, 0, 0);
      __builtin_amdgcn_s_setprio(0);
      // (d) B(t+1) landed: younger = A(t+1) 8 + B(t+2) 4
      if (t == NT - 2) { asm volatile("s_waitcnt vmcnt(8)" ::: "memory"); }
      else             { asm volatile("s_waitcnt vmcnt(12)" ::: "memory"); }
      __builtin_amdgcn_s_barrier();
      cur = (cur == 2) ? 0 : cur + 1;
    }
    // ================= odd half: t = 2*tp+1, consume pA1, load pA0 =================
    {
      const int t = 2 * tp + 1;
      const int curo = cur * BBUF;
      const int nxto = ((cur == 0) ? 2 : cur - 1) * BBUF;   // (t+2)%3
      const u16* aT1 = aBase + (size_t)(t + 1) * BK;

      if (t + 1 < NT) {
#pragma unroll
        for (int m = 0; m < 4; ++m)
#pragma unroll
          for (int kk = 0; kk < 2; ++kk)
            pA0[m][kk] = *(const bf16x8*)(aT1 + m * MSTRIDE + kk * 32);
      }
      if (t + 2 < NT) {
        const int k0n = (t + 2) * BK;
#pragma unroll
        for (int it = 0; it < 4; ++it) gload_lds16(Bb + srcB[it] + k0n, &lds[nxto + dstB[it]]);
      }
      __builtin_amdgcn_sched_barrier(0);
      bf16x8 b_frag[4][2];
#pragma unroll
      for (int n = 0; n < 4; ++n)
#pragma unroll
        for (int kk = 0; kk < 2; ++kk)
          b_frag[n][kk] = *(const bf16x8*)&lds[curo + rB[n] * 64 + (((kk * 4 + l4) ^ (rB[n] & 7)) * 8)];
      asm volatile("s_waitcnt lgkmcnt(0)" ::: "memory");
      __builtin_amdgcn_sched_barrier(0);
      __builtin_amdgcn_s_setprio(1);
#pragma unroll
      for (int kk = 0; kk < 2; ++kk)
#pragma unroll
        for (int m = 0; m < 4; ++m)
#pragma unroll
          for (int n = 0; n < 4; ++n)
            acc[m][n] = __builtin_amdgcn_mfma_f32_16x16x32_bf16(pA1[m][kk], b_frag[n][kk], acc[m][n], 0, 0, 0);
      __builtin_amdgcn_s_setprio(0);
      if (t == NT - 1)      { asm volatile("s_waitcnt vmcnt(0)"  ::: "memory"); }
      else                  { asm volatile("s_waitcnt vmcnt(12)" ::: "memory"); }
      __builtin_amdgcn_s_barrier();
      cur = (cur == 2) ? 0 : cur + 1;
    }
  }

  // epilogue: C/D layout col=lane&15, row=(lane>>4)*4+reg (round-1-verified)
  const int row0 = bm * BM + wr * 64 + l4 * 4;
  const int col0 = bn * BN + wc * 64 + lc;
#pragma unroll
  for (int m = 0; m < 4; ++m)
#pragma unroll
    for (int n = 0; n < 4; ++n) {
      float* cp = C + (size_t)(row0 + m * 16) * NOUT + col0 + n * 16;
#pragma unroll
      for (int r = 0; r < 4; ++r)
        cp[(size_t)r * NOUT] = acc[m][n][r];
    }
}

extern "C" void kernel_launch(void* const* d_in, const int* in_sizes, int n_in,
                              void* d_out, int out_size, void* d_ws, size_t ws_size,
                              hipStream_t stream) {
  const float* x  = (const float*)d_in[0];
  const float* bw = (const float*)d_in[1];
  const float* sw = (const float*)d_in[2];
  const float* ss = (const float*)d_in[3];
  float* out = (float*)d_out;

  u16* Bt = (u16*)d_ws;                                    // 1024*9216*2 B
  u16* A  = (u16*)((char*)d_ws + (size_t)NOUT * KTOT * 2); // 8192*9216*2 B

  prep_all<<<PB_BLOCKS + PS_BLOCKS + BA_BLOCKS, 256, 0, stream>>>(x, bw, sw, ss, Bt, A);
  kan_gemm<<<256, 512, 0, stream>>>(A, Bt, out);
}